// Round 5
// baseline (171.090 us; speedup 1.0000x reference)
//
#include <hip/hip_runtime.h>

#define NPIX   1024
#define BATCH  16
#define CIN    256
#define NQKV   1536
#define INNER  512
#define HEADS  8
#define DH     64

typedef __attribute__((ext_vector_type(8))) short short8;   // 8 bf16 = 4 VGPRs
typedef __attribute__((ext_vector_type(4))) float f32x4;

__device__ __forceinline__ ushort f2b(float f) {
    union { float f; unsigned u; } v; v.f = f;
    unsigned r = v.u + 0x7fffu + ((v.u >> 16) & 1u);   // RNE
    return (ushort)(r >> 16);
}
__device__ __forceinline__ float b2f(ushort u) {
    union { float f; unsigned u; } v; v.u = ((unsigned)u) << 16; return v.f;
}

// ---------------------------------------------------------------------------
// prep_all: blocks [0,4096): x [b][c][p] f32 -> xT [b][p][c] bf16 (transpose)
//           blocks [4096,6144): Wq/Wkv -> Wqkv_b [1536][256]; Wo -> Wob bf16
// ---------------------------------------------------------------------------
__global__ __launch_bounds__(256) void prep_all(const float* __restrict__ x,
        const float* __restrict__ Wq, const float* __restrict__ Wkv,
        const float* __restrict__ Wo, ushort* __restrict__ xT,
        ushort* __restrict__ Wqkv_b, ushort* __restrict__ Wob) {
    const int bid = blockIdx.x;
    if (bid < 4096) {
        __shared__ float tile[32][33];
        const int b   = bid >> 8;
        const int rem = bid & 255;             // 32 p-tiles x 8 c-tiles
        const int p0  = (rem & 31) * 32;
        const int c0  = (rem >> 5) * 32;
        const int tx = threadIdx.x & 31, ty = threadIdx.x >> 5;
#pragma unroll
        for (int i = 0; i < 4; i++) {
            int c = ty + i * 8;
            tile[c][tx] = x[(b * CIN + c0 + c) * NPIX + p0 + tx];
        }
        __syncthreads();
#pragma unroll
        for (int i = 0; i < 4; i++) {
            int p = ty + i * 8;
            xT[(b * NPIX + p0 + p) * CIN + c0 + tx] = f2b(tile[tx][p]);
        }
    } else {
        int i = (bid - 4096) * 256 + threadIdx.x;   // 524288 weight elements
        if (i < NQKV * CIN)
            Wqkv_b[i] = f2b(i < INNER * CIN ? Wq[i] : Wkv[i - INNER * CIN]);
        int j = i - NQKV * CIN;
        if (j >= 0 && j < CIN * INNER)
            Wob[j] = f2b(Wo[j]);
    }
}

// ---------------------------------------------------------------------------
// GEMM1, no-LDS register-tile: D[o][p] = sum_c Wqkv_b[o][c] * xT[p][c]
// Each lane loads its MFMA fragments straight from global (16B, L2-served).
// No barriers, no LDS: pure load+MFMA stream. XCD-chunked block swizzle
// keeps each XCD's xT slab + full W in its own L2.
// ---------------------------------------------------------------------------
__global__ __launch_bounds__(256) void gemm_qkv(const ushort* __restrict__ xT,
        const ushort* __restrict__ Wb, ushort* __restrict__ qkv) {
    const int bid = blockIdx.x;
    const int swz = (bid & 7) * 192 + (bid >> 3);   // 1536 = 8 XCD * 192
    const int m0  = (swz / 12) * 128;               // pixel tile
    const int n0  = (swz % 12) * 128;               // o tile
    const int t    = threadIdx.x;
    const int wave = t >> 6, lane = t & 63;
    const int wo = (wave & 1) * 64, wp = (wave >> 1) * 64;
    const int lrow = lane & 15, loct = lane >> 4;

    const ushort* aB = Wb + (n0 + wo + lrow) * CIN + loct * 8;
    const ushort* bB = xT + (m0 + wp + lrow) * CIN + loct * 8;

    f32x4 acc[4][4];
#pragma unroll
    for (int i = 0; i < 4; i++)
#pragma unroll
        for (int j = 0; j < 4; j++) acc[i][j] = (f32x4){0.f, 0.f, 0.f, 0.f};

#pragma unroll 4
    for (int c0 = 0; c0 < CIN; c0 += 32) {
        short8 a[4], bb[4];
#pragma unroll
        for (int i = 0; i < 4; i++)
            a[i] = *reinterpret_cast<const short8*>(aB + i * 16 * CIN + c0);
#pragma unroll
        for (int j = 0; j < 4; j++)
            bb[j] = *reinterpret_cast<const short8*>(bB + j * 16 * CIN + c0);
#pragma unroll
        for (int i = 0; i < 4; i++)
#pragma unroll
            for (int j = 0; j < 4; j++)
                acc[i][j] = __builtin_amdgcn_mfma_f32_16x16x32_bf16(a[i], bb[j], acc[i][j], 0, 0, 0);
    }

#pragma unroll
    for (int i = 0; i < 4; i++)
#pragma unroll
        for (int j = 0; j < 4; j++) {
            int gm = m0 + wp + j * 16 + lrow;
            int go = n0 + wo + i * 16 + loct * 4;
            ushort4 pk = make_ushort4(f2b(acc[i][j].x), f2b(acc[i][j].y),
                                      f2b(acc[i][j].z), f2b(acc[i][j].w));
            *reinterpret_cast<ushort4*>(&qkv[gm * NQKV + go]) = pk;
        }
}

// ---------------------------------------------------------------------------
// Attention: one wave per pixel m; lane = (h, d-octet). XCD-chunked swizzle.
// Zero-pad softmax semantics (OOB logit = exact 0, included in softmax).
// ---------------------------------------------------------------------------
__global__ __launch_bounds__(256) void attn_kernel(const ushort* __restrict__ qkv,
        ushort* __restrict__ po, float* __restrict__ attn_out) {
    const int bid = blockIdx.x;
    const int swz = (bid & 7) * 512 + (bid >> 3);   // 4096 = 8 XCD * 512
    const int m    = swz * 4 + (threadIdx.x >> 6);
    const int lane = threadIdx.x & 63;
    const int h = lane >> 3, sub = lane & 7;
    const int b = m >> 10;
    const int p = m & 1023;
    const int py = p >> 5, px = p & 31;
    const int hd8 = h * DH + sub * 8;

    short8 qv = *reinterpret_cast<const short8*>(&qkv[m * NQKV + hd8]);
    float qf[8];
#pragma unroll
    for (int j = 0; j < 8; j++) qf[j] = b2f((ushort)qv[j]);

    float dots[9];
    int   nb[9];
    bool  ok[9];
#pragma unroll
    for (int w = 0; w < 9; w++) {
        int dy = w / 3 - 1, dx = w % 3 - 1;
        int ny = py + dy, nx = px + dx;
        bool in = ((unsigned)ny < 32u) && ((unsigned)nx < 32u);
        ok[w] = in;
        int nm = b * NPIX + ny * 32 + nx;
        nb[w] = nm;
        float d = 0.f;
        if (in) {
            short8 kv8 = *reinterpret_cast<const short8*>(&qkv[nm * NQKV + 512 + hd8]);
#pragma unroll
            for (int j = 0; j < 8; j++) d = fmaf(qf[j], b2f((ushort)kv8[j]), d);
        }
        d += __shfl_xor(d, 1);
        d += __shfl_xor(d, 2);
        d += __shfl_xor(d, 4);
        dots[w] = d * 0.125f;   // OOB: exact 0 (zero-pad semantics)
    }

    float mx = dots[0];
#pragma unroll
    for (int w = 1; w < 9; w++) mx = fmaxf(mx, dots[w]);
    float e[9], s = 0.f;
#pragma unroll
    for (int w = 0; w < 9; w++) { e[w] = __expf(dots[w] - mx); s += e[w]; }
    const float inv = 1.f / s;

    float o[8] = {};
#pragma unroll
    for (int w = 0; w < 9; w++) {
        if (ok[w]) {
            short8 vv = *reinterpret_cast<const short8*>(&qkv[nb[w] * NQKV + 1024 + hd8]);
            float pw = e[w] * inv;
#pragma unroll
            for (int j = 0; j < 8; j++) o[j] = fmaf(pw, b2f((ushort)vv[j]), o[j]);
        }
    }
    short8 r;
#pragma unroll
    for (int j = 0; j < 8; j++) r[j] = (short)f2b(o[j]);
    *reinterpret_cast<short8*>(&po[m * INNER + hd8]) = r;

    float* ab = &attn_out[((b * HEADS + h) * NPIX + p) * 9];
    ab[sub] = e[sub] * inv;
    if (sub == 0) ab[8] = e[8] * inv;
}

// ---------------------------------------------------------------------------
// GEMM2, no-LDS register-tile: D[p][o] = sum_i po[p][i] * Wob[o][i] (+ bias)
// ---------------------------------------------------------------------------
__global__ __launch_bounds__(256) void gemm_out(const ushort* __restrict__ po,
        const ushort* __restrict__ Wob, const float* __restrict__ bo,
        float* __restrict__ out) {
    const int bid = blockIdx.x;
    const int swz = (bid & 7) * 32 + (bid >> 3);    // 256 = 8 XCD * 32
    const int m0  = (swz >> 1) * 128;               // pixel tile
    const int n0  = (swz & 1) * 128;                // o tile
    const int t    = threadIdx.x;
    const int wave = t >> 6, lane = t & 63;
    const int wm = (wave >> 1) * 64, wn = (wave & 1) * 64;
    const int lrow = lane & 15, loct = lane >> 4;

    const ushort* aB = po  + (m0 + wm + lrow) * INNER + loct * 8;
    const ushort* bB = Wob + (n0 + wn + lrow) * INNER + loct * 8;

    f32x4 acc[4][4];
#pragma unroll
    for (int i = 0; i < 4; i++)
#pragma unroll
        for (int j = 0; j < 4; j++) acc[i][j] = (f32x4){0.f, 0.f, 0.f, 0.f};

#pragma unroll 4
    for (int c0 = 0; c0 < INNER; c0 += 32) {
        short8 a[4], bb[4];
#pragma unroll
        for (int i = 0; i < 4; i++)
            a[i] = *reinterpret_cast<const short8*>(aB + i * 16 * INNER + c0);
#pragma unroll
        for (int j = 0; j < 4; j++)
            bb[j] = *reinterpret_cast<const short8*>(bB + j * 16 * INNER + c0);
#pragma unroll
        for (int i = 0; i < 4; i++)
#pragma unroll
            for (int j = 0; j < 4; j++)
                acc[i][j] = __builtin_amdgcn_mfma_f32_16x16x32_bf16(a[i], bb[j], acc[i][j], 0, 0, 0);
    }

    const int bb_ = m0 >> 10;
    const int p0  = m0 & 1023;
#pragma unroll
    for (int i = 0; i < 4; i++)
#pragma unroll
        for (int j = 0; j < 4; j++) {
            int o  = n0 + wn + j * 16 + lrow;
            int pp = p0 + wm + i * 16 + loct * 4;
            float bias = bo[o];
            float4 v = make_float4(acc[i][j].x + bias, acc[i][j].y + bias,
                                   acc[i][j].z + bias, acc[i][j].w + bias);
            *reinterpret_cast<float4*>(&out[(bb_ * CIN + o) * NPIX + pp]) = v;
        }
}

// ---------------------------------------------------------------------------
extern "C" void kernel_launch(void* const* d_in, const int* in_sizes, int n_in,
                              void* d_out, int out_size, void* d_ws, size_t ws_size,
                              hipStream_t stream) {
    const float* x   = (const float*)d_in[0];
    const float* Wq  = (const float*)d_in[1];
    const float* Wkv = (const float*)d_in[2];
    const float* Wo  = (const float*)d_in[3];
    const float* bo  = (const float*)d_in[4];

    float* out  = (float*)d_out;
    float* attn = out + BATCH * CIN * NPIX;

    ushort* xT     = (ushort*)d_ws;               // 16384*256
    ushort* Wqkv_b = xT + 16384 * CIN;            // 1536*256
    ushort* Wob    = Wqkv_b + NQKV * CIN;         // 256*512
    ushort* qkv    = Wob + CIN * INNER;           // 16384*1536
    ushort* po     = qkv + 16384 * NQKV;          // 16384*512

    prep_all<<<6144, 256, 0, stream>>>(x, Wq, Wkv, Wo, xT, Wqkv_b, Wob);

    gemm_qkv<<<1536, 256, 0, stream>>>(xT, Wqkv_b, qkv);

    attn_kernel<<<16384 / 4, 256, 0, stream>>>(qkv, po, attn);

    gemm_out<<<256, 256, 0, stream>>>(po, Wob, bo, out);
}

// Round 8
// 155.625 us; speedup vs baseline: 1.0994x; 1.0994x over previous
//
#include <hip/hip_runtime.h>

#define NPIX   1024
#define BATCH  16
#define CIN    256
#define NQKV   1536
#define INNER  512
#define HEADS  8
#define DH     64

typedef __attribute__((ext_vector_type(8))) short short8;   // 8 bf16 = 4 VGPRs
typedef __attribute__((ext_vector_type(4))) float f32x4;

__device__ __forceinline__ ushort f2b(float f) {
    union { float f; unsigned u; } v; v.f = f;
    unsigned r = v.u + 0x7fffu + ((v.u >> 16) & 1u);   // RNE
    return (ushort)(r >> 16);
}
__device__ __forceinline__ float b2f(ushort u) {
    union { float f; unsigned u; } v; v.u = ((unsigned)u) << 16; return v.f;
}
__device__ __forceinline__ void async16(const void* g, void* l) {
    __builtin_amdgcn_global_load_lds((const __attribute__((address_space(1))) void*)g,
                                     (__attribute__((address_space(3))) void*)l, 16, 0, 0);
}

// ---------------------------------------------------------------------------
// prep_all: blocks [0,4096): x [b][c][p] f32 -> xT [b][p][c] bf16 (transpose)
//           blocks [4096,6144): Wq/Wkv -> Wqkv_b [1536][256]; Wo -> Wob bf16
// ---------------------------------------------------------------------------
__global__ __launch_bounds__(256) void prep_all(const float* __restrict__ x,
        const float* __restrict__ Wq, const float* __restrict__ Wkv,
        const float* __restrict__ Wo, ushort* __restrict__ xT,
        ushort* __restrict__ Wqkv_b, ushort* __restrict__ Wob) {
    const int bid = blockIdx.x;
    if (bid < 4096) {
        __shared__ float tile[32][33];
        const int b   = bid >> 8;
        const int rem = bid & 255;
        const int p0  = (rem & 31) * 32;
        const int c0  = (rem >> 5) * 32;
        const int tx = threadIdx.x & 31, ty = threadIdx.x >> 5;
#pragma unroll
        for (int i = 0; i < 4; i++) {
            int c = ty + i * 8;
            tile[c][tx] = x[(b * CIN + c0 + c) * NPIX + p0 + tx];
        }
        __syncthreads();
#pragma unroll
        for (int i = 0; i < 4; i++) {
            int p = ty + i * 8;
            xT[(b * NPIX + p0 + p) * CIN + c0 + tx] = f2b(tile[tx][p]);
        }
    } else {
        int i = (bid - 4096) * 256 + threadIdx.x;
        if (i < NQKV * CIN)
            Wqkv_b[i] = f2b(i < INNER * CIN ? Wq[i] : Wkv[i - INNER * CIN]);
        int j = i - NQKV * CIN;
        if (j >= 0 && j < CIN * INNER)
            Wob[j] = f2b(Wo[j]);
    }
}

// ---------------------------------------------------------------------------
// GEMM1 (MFMA, 2-phase dbuf staged): D[o][p] = sum_c Wqkv_b[o][c] * xT[p][c]
// Validated round-4 structure. XCD-chunked swizzle.
// ---------------------------------------------------------------------------
__global__ __launch_bounds__(256) void gemm_qkv(const ushort* __restrict__ xT,
        const ushort* __restrict__ Wb, ushort* __restrict__ qkv) {
    __shared__ ushort As[2][128][32];   // rows = o
    __shared__ ushort Bs[2][128][32];   // rows = p
    const int bid = blockIdx.x;
    const int swz = (bid & 7) * 192 + (bid >> 3);   // 1536 = 8 XCD * 192
    const int m0  = (swz / 12) * 128;
    const int n0  = (swz % 12) * 128;
    const int t    = threadIdx.x;
    const int wave = t >> 6, lane = t & 63;
    const int wo = (wave & 1) * 64, wp = (wave >> 1) * 64;
    const int lrow = lane & 15, loct = lane >> 4;

    const int srow = t >> 2;
    const int skb  = (t & 3) * 8;
    const ushort* gA = Wb + (n0 + srow) * CIN + skb;
    const ushort* gB = xT + (m0 + srow) * CIN + skb;

    f32x4 acc[4][4];
#pragma unroll
    for (int i = 0; i < 4; i++)
#pragma unroll
        for (int j = 0; j < 4; j++) acc[i][j] = (f32x4){0.f, 0.f, 0.f, 0.f};

#define STAGE1(buf, c0)                                             \
    do {                                                            \
        async16(gA + (c0),            &As[buf][wave * 16][0]);      \
        async16(gA + 64 * CIN + (c0), &As[buf][64 + wave * 16][0]); \
        async16(gB + (c0),            &Bs[buf][wave * 16][0]);      \
        async16(gB + 64 * CIN + (c0), &Bs[buf][64 + wave * 16][0]); \
    } while (0)

    STAGE1(0, 0);
    __syncthreads();
    int cur = 0;
    const int NT = CIN / 32;               // 8
    for (int it = 0; it < NT; ++it) {
        if (it + 1 < NT) STAGE1(cur ^ 1, (it + 1) * 32);
        short8 a[4], bb[4];
#pragma unroll
        for (int i = 0; i < 4; i++)
            a[i] = *reinterpret_cast<const short8*>(&As[cur][wo + i * 16 + lrow][loct * 8]);
#pragma unroll
        for (int j = 0; j < 4; j++)
            bb[j] = *reinterpret_cast<const short8*>(&Bs[cur][wp + j * 16 + lrow][loct * 8]);
#pragma unroll
        for (int i = 0; i < 4; i++)
#pragma unroll
            for (int j = 0; j < 4; j++)
                acc[i][j] = __builtin_amdgcn_mfma_f32_16x16x32_bf16(a[i], bb[j], acc[i][j], 0, 0, 0);
        __syncthreads();
        cur ^= 1;
    }
#undef STAGE1

#pragma unroll
    for (int i = 0; i < 4; i++)
#pragma unroll
        for (int j = 0; j < 4; j++) {
            int gm = m0 + wp + j * 16 + lrow;
            int go = n0 + wo + i * 16 + loct * 4;
            ushort4 pk = make_ushort4(f2b(acc[i][j].x), f2b(acc[i][j].y),
                                      f2b(acc[i][j].z), f2b(acc[i][j].w));
            *reinterpret_cast<ushort4*>(&qkv[gm * NQKV + go]) = pk;
        }
}

// ---------------------------------------------------------------------------
// Fused attention + output projection.
// Block = 16 consecutive pixels, 16 waves (1024 thr); wave w owns pixel
// m = swz*16 + w, lane = (h, d-octet) as before. Attention math identical
// to the validated kernel; po row goes to LDS (padded [16][520]) instead of
// global. After one barrier, wave w computes out rows o in [16w, 16w+16):
// 16 x mfma(Wob-frag(global, L2-hot), po-frag(LDS)), bias, coalesced store.
// ---------------------------------------------------------------------------
__global__ __launch_bounds__(1024, 1) void attn_out_fused(
        const ushort* __restrict__ qkv, const ushort* __restrict__ Wob,
        const float* __restrict__ bo, float* __restrict__ out,
        float* __restrict__ attn_out_) {
    __shared__ ushort poS[16][520];      // 16 pixels x 512 bf16, +8 pad
    const int bid = blockIdx.x;
    const int swz = (bid & 7) * 128 + (bid >> 3);   // 1024 = 8 XCD * 128
    const int wave = threadIdx.x >> 6;
    const int lane = threadIdx.x & 63;
    const int m = swz * 16 + wave;
    const int h = lane >> 3, sub = lane & 7;
    const int b = m >> 10;
    const int p = m & 1023;
    const int py = p >> 5, px = p & 31;
    const int hd8 = h * DH + sub * 8;

    // ---- attention (validated math, zero-pad softmax semantics) ----
    short8 qv = *reinterpret_cast<const short8*>(&qkv[m * NQKV + hd8]);
    float qf[8];
#pragma unroll
    for (int j = 0; j < 8; j++) qf[j] = b2f((ushort)qv[j]);

    float dots[9];
    int   nb[9];
    bool  ok[9];
#pragma unroll
    for (int w = 0; w < 9; w++) {
        int dy = w / 3 - 1, dx = w % 3 - 1;
        int ny = py + dy, nx = px + dx;
        bool in = ((unsigned)ny < 32u) && ((unsigned)nx < 32u);
        ok[w] = in;
        int nm = b * NPIX + ny * 32 + nx;
        nb[w] = nm;
        float d = 0.f;
        if (in) {
            short8 kv8 = *reinterpret_cast<const short8*>(&qkv[nm * NQKV + 512 + hd8]);
#pragma unroll
            for (int j = 0; j < 8; j++) d = fmaf(qf[j], b2f((ushort)kv8[j]), d);
        }
        d += __shfl_xor(d, 1);
        d += __shfl_xor(d, 2);
        d += __shfl_xor(d, 4);
        dots[w] = d * 0.125f;   // OOB: exact 0
    }

    float mx = dots[0];
#pragma unroll
    for (int w = 1; w < 9; w++) mx = fmaxf(mx, dots[w]);
    float e[9], s = 0.f;
#pragma unroll
    for (int w = 0; w < 9; w++) { e[w] = __expf(dots[w] - mx); s += e[w]; }
    const float inv = 1.f / s;

    float o[8] = {};
#pragma unroll
    for (int w = 0; w < 9; w++) {
        if (ok[w]) {
            short8 vv = *reinterpret_cast<const short8*>(&qkv[nb[w] * NQKV + 1024 + hd8]);
            float pw = e[w] * inv;
#pragma unroll
            for (int j = 0; j < 8; j++) o[j] = fmaf(pw, b2f((ushort)vv[j]), o[j]);
        }
    }
    short8 r;
#pragma unroll
    for (int j = 0; j < 8; j++) r[j] = (short)f2b(o[j]);
    *reinterpret_cast<short8*>(&poS[wave][hd8]) = r;   // row stride 1040B, 16B-aligned

    float* ab = &attn_out_[((b * HEADS + h) * NPIX + p) * 9];
    ab[sub] = e[sub] * inv;
    if (sub == 0) ab[8] = e[8] * inv;

    __syncthreads();

    // ---- fused output projection: wave w -> out rows [16w, 16w+16) ----
    const int lrow = lane & 15, loct = lane >> 4;
    const int o_base = wave * 16;
    const ushort* wb = Wob + (o_base + lrow) * INNER + loct * 8;
    f32x4 acc = (f32x4){0.f, 0.f, 0.f, 0.f};
#pragma unroll
    for (int ks = 0; ks < 16; ks++) {
        short8 wfrag = *reinterpret_cast<const short8*>(wb + ks * 32);
        short8 pfrag = *reinterpret_cast<const short8*>(&poS[lrow][loct * 8 + ks * 32]);
        acc = __builtin_amdgcn_mfma_f32_16x16x32_bf16(wfrag, pfrag, acc, 0, 0, 0);
    }
    const int p0b = (swz * 16) & 1023;
    float4 b4 = *reinterpret_cast<const float4*>(&bo[o_base + loct * 4]);
    float bias[4] = {b4.x, b4.y, b4.z, b4.w};
#pragma unroll
    for (int rr = 0; rr < 4; rr++) {
        int oo = o_base + loct * 4 + rr;
        out[(b * CIN + oo) * NPIX + p0b + lrow] = acc[rr] + bias[rr];
    }
}

// ---------------------------------------------------------------------------
extern "C" void kernel_launch(void* const* d_in, const int* in_sizes, int n_in,
                              void* d_out, int out_size, void* d_ws, size_t ws_size,
                              hipStream_t stream) {
    const float* x   = (const float*)d_in[0];
    const float* Wq  = (const float*)d_in[1];
    const float* Wkv = (const float*)d_in[2];
    const float* Wo  = (const float*)d_in[3];
    const float* bo  = (const float*)d_in[4];

    float* out  = (float*)d_out;
    float* attn = out + BATCH * CIN * NPIX;

    ushort* xT     = (ushort*)d_ws;               // 16384*256
    ushort* Wqkv_b = xT + 16384 * CIN;            // 1536*256
    ushort* Wob    = Wqkv_b + NQKV * CIN;         // 256*512
    ushort* qkv    = Wob + CIN * INNER;           // 16384*1536

    prep_all<<<6144, 256, 0, stream>>>(x, Wq, Wkv, Wo, xT, Wqkv_b, Wob);

    gemm_qkv<<<1536, 256, 0, stream>>>(xT, Wqkv_b, qkv);

    attn_out_fused<<<1024, 1024, 0, stream>>>(qkv, Wob, bo, out, attn);
}

// Round 9
// 139.278 us; speedup vs baseline: 1.2284x; 1.1174x over previous
//
#include <hip/hip_runtime.h>

#define NPIX   1024
#define BATCH  16
#define CIN    256
#define NQKV   1536
#define INNER  512
#define HEADS  8
#define DH     64

typedef __attribute__((ext_vector_type(8))) short short8;   // 8 bf16 = 4 VGPRs
typedef __attribute__((ext_vector_type(4))) float f32x4;

__device__ __forceinline__ ushort f2b(float f) {
    union { float f; unsigned u; } v; v.f = f;
    unsigned r = v.u + 0x7fffu + ((v.u >> 16) & 1u);   // RNE
    return (ushort)(r >> 16);
}
__device__ __forceinline__ float b2f(ushort u) {
    union { float f; unsigned u; } v; v.u = ((unsigned)u) << 16; return v.f;
}
__device__ __forceinline__ void async16(const void* g, void* l) {
    __builtin_amdgcn_global_load_lds((const __attribute__((address_space(1))) void*)g,
                                     (__attribute__((address_space(3))) void*)l, 16, 0, 0);
}

// ---------------------------------------------------------------------------
// prep_all: blocks [0,1024): x [b][c][p] f32 -> xT [b][p][c] bf16.
//   64c x 64p tile; float4 loads (256B runs), LDS [64][65] (conflict-free
//   both phases), ushort8 stores (128B contiguous runs along c).
// blocks [1024,3072): Wq/Wkv -> Wqkv_b [1536][256]; Wo -> Wob bf16.
// ---------------------------------------------------------------------------
__global__ __launch_bounds__(256) void prep_all(const float* __restrict__ x,
        const float* __restrict__ Wq, const float* __restrict__ Wkv,
        const float* __restrict__ Wo, ushort* __restrict__ xT,
        ushort* __restrict__ Wqkv_b, ushort* __restrict__ Wob) {
    const int bid = blockIdx.x;
    const int t   = threadIdx.x;
    if (bid < 1024) {
        __shared__ float tf[64][65];
        const int b   = bid >> 6;              // 16 b x (16 p-tiles x 4 c-tiles)
        const int rem = bid & 63;
        const int p0  = (rem & 15) * 64;
        const int c0  = (rem >> 4) * 64;
#pragma unroll
        for (int ps = 0; ps < 4; ps++) {
            int c = (t >> 4) + ps * 16;
            int p = (t & 15) * 4;
            float4 v = *reinterpret_cast<const float4*>(&x[(b * CIN + c0 + c) * NPIX + p0 + p]);
            tf[c][p] = v.x; tf[c][p + 1] = v.y; tf[c][p + 2] = v.z; tf[c][p + 3] = v.w;
        }
        __syncthreads();
#pragma unroll
        for (int ps = 0; ps < 2; ps++) {
            int p  = (t >> 3) + ps * 32;
            int c8 = (t & 7) * 8;
            short8 r;
#pragma unroll
            for (int j = 0; j < 8; j++) r[j] = (short)f2b(tf[c8 + j][p]);
            *reinterpret_cast<short8*>(&xT[(b * NPIX + p0 + p) * CIN + c0 + c8]) = r;
        }
    } else {
        int i = (bid - 1024) * 256 + t;        // 524288 weight elements
        if (i < NQKV * CIN)
            Wqkv_b[i] = f2b(i < INNER * CIN ? Wq[i] : Wkv[i - INNER * CIN]);
        int j = i - NQKV * CIN;
        if (j >= 0 && j < CIN * INNER)
            Wob[j] = f2b(Wo[j]);
    }
}

// ---------------------------------------------------------------------------
// GEMM1 (MFMA, 2-phase dbuf staged): D[o][p] = sum_c Wqkv_b[o][c] * xT[p][c]
// Validated round-4 structure. XCD-chunked swizzle.
// ---------------------------------------------------------------------------
__global__ __launch_bounds__(256) void gemm_qkv(const ushort* __restrict__ xT,
        const ushort* __restrict__ Wb, ushort* __restrict__ qkv) {
    __shared__ ushort As[2][128][32];   // rows = o
    __shared__ ushort Bs[2][128][32];   // rows = p
    const int bid = blockIdx.x;
    const int swz = (bid & 7) * 192 + (bid >> 3);   // 1536 = 8 XCD * 192
    const int m0  = (swz / 12) * 128;
    const int n0  = (swz % 12) * 128;
    const int t    = threadIdx.x;
    const int wave = t >> 6, lane = t & 63;
    const int wo = (wave & 1) * 64, wp = (wave >> 1) * 64;
    const int lrow = lane & 15, loct = lane >> 4;

    const int srow = t >> 2;
    const int skb  = (t & 3) * 8;
    const ushort* gA = Wb + (n0 + srow) * CIN + skb;
    const ushort* gB = xT + (m0 + srow) * CIN + skb;

    f32x4 acc[4][4];
#pragma unroll
    for (int i = 0; i < 4; i++)
#pragma unroll
        for (int j = 0; j < 4; j++) acc[i][j] = (f32x4){0.f, 0.f, 0.f, 0.f};

#define STAGE1(buf, c0)                                             \
    do {                                                            \
        async16(gA + (c0),            &As[buf][wave * 16][0]);      \
        async16(gA + 64 * CIN + (c0), &As[buf][64 + wave * 16][0]); \
        async16(gB + (c0),            &Bs[buf][wave * 16][0]);      \
        async16(gB + 64 * CIN + (c0), &Bs[buf][64 + wave * 16][0]); \
    } while (0)

    STAGE1(0, 0);
    __syncthreads();
    int cur = 0;
    const int NT = CIN / 32;               // 8
    for (int it = 0; it < NT; ++it) {
        if (it + 1 < NT) STAGE1(cur ^ 1, (it + 1) * 32);
        short8 a[4], bb[4];
#pragma unroll
        for (int i = 0; i < 4; i++)
            a[i] = *reinterpret_cast<const short8*>(&As[cur][wo + i * 16 + lrow][loct * 8]);
#pragma unroll
        for (int j = 0; j < 4; j++)
            bb[j] = *reinterpret_cast<const short8*>(&Bs[cur][wp + j * 16 + lrow][loct * 8]);
#pragma unroll
        for (int i = 0; i < 4; i++)
#pragma unroll
            for (int j = 0; j < 4; j++)
                acc[i][j] = __builtin_amdgcn_mfma_f32_16x16x32_bf16(a[i], bb[j], acc[i][j], 0, 0, 0);
        __syncthreads();
        cur ^= 1;
    }
#undef STAGE1

#pragma unroll
    for (int i = 0; i < 4; i++)
#pragma unroll
        for (int j = 0; j < 4; j++) {
            int gm = m0 + wp + j * 16 + lrow;
            int go = n0 + wo + i * 16 + loct * 4;
            ushort4 pk = make_ushort4(f2b(acc[i][j].x), f2b(acc[i][j].y),
                                      f2b(acc[i][j].z), f2b(acc[i][j].w));
            *reinterpret_cast<ushort4*>(&qkv[gm * NQKV + go]) = pk;
        }
}

// ---------------------------------------------------------------------------
// Attention (validated r5 standalone): one wave per pixel m; lane=(h,d-octet).
// XCD-chunked swizzle. Zero-pad softmax semantics.
// ---------------------------------------------------------------------------
__global__ __launch_bounds__(256) void attn_kernel(const ushort* __restrict__ qkv,
        ushort* __restrict__ po, float* __restrict__ attn_out) {
    const int bid = blockIdx.x;
    const int swz = (bid & 7) * 512 + (bid >> 3);   // 4096 = 8 XCD * 512
    const int m    = swz * 4 + (threadIdx.x >> 6);
    const int lane = threadIdx.x & 63;
    const int h = lane >> 3, sub = lane & 7;
    const int b = m >> 10;
    const int p = m & 1023;
    const int py = p >> 5, px = p & 31;
    const int hd8 = h * DH + sub * 8;

    short8 qv = *reinterpret_cast<const short8*>(&qkv[m * NQKV + hd8]);
    float qf[8];
#pragma unroll
    for (int j = 0; j < 8; j++) qf[j] = b2f((ushort)qv[j]);

    float dots[9];
    int   nb[9];
    bool  ok[9];
#pragma unroll
    for (int w = 0; w < 9; w++) {
        int dy = w / 3 - 1, dx = w % 3 - 1;
        int ny = py + dy, nx = px + dx;
        bool in = ((unsigned)ny < 32u) && ((unsigned)nx < 32u);
        ok[w] = in;
        int nm = b * NPIX + ny * 32 + nx;
        nb[w] = nm;
        float d = 0.f;
        if (in) {
            short8 kv8 = *reinterpret_cast<const short8*>(&qkv[nm * NQKV + 512 + hd8]);
#pragma unroll
            for (int j = 0; j < 8; j++) d = fmaf(qf[j], b2f((ushort)kv8[j]), d);
        }
        d += __shfl_xor(d, 1);
        d += __shfl_xor(d, 2);
        d += __shfl_xor(d, 4);
        dots[w] = d * 0.125f;   // OOB: exact 0 (zero-pad semantics)
    }

    float mx = dots[0];
#pragma unroll
    for (int w = 1; w < 9; w++) mx = fmaxf(mx, dots[w]);
    float e[9], s = 0.f;
#pragma unroll
    for (int w = 0; w < 9; w++) { e[w] = __expf(dots[w] - mx); s += e[w]; }
    const float inv = 1.f / s;

    float o[8] = {};
#pragma unroll
    for (int w = 0; w < 9; w++) {
        if (ok[w]) {
            short8 vv = *reinterpret_cast<const short8*>(&qkv[nb[w] * NQKV + 1024 + hd8]);
            float pw = e[w] * inv;
#pragma unroll
            for (int j = 0; j < 8; j++) o[j] = fmaf(pw, b2f((ushort)vv[j]), o[j]);
        }
    }
    short8 r;
#pragma unroll
    for (int j = 0; j < 8; j++) r[j] = (short)f2b(o[j]);
    *reinterpret_cast<short8*>(&po[m * INNER + hd8]) = r;

    float* ab = &attn_out[((b * HEADS + h) * NPIX + p) * 9];
    ab[sub] = e[sub] * inv;
    if (sub == 0) ab[8] = e[8] * inv;
}

// ---------------------------------------------------------------------------
// GEMM2 (MFMA, 2-phase dbuf staged, validated r4): D[p][o] = po x Wob + bias
// ---------------------------------------------------------------------------
__global__ __launch_bounds__(256) void gemm_out(const ushort* __restrict__ po,
        const ushort* __restrict__ Wob, const float* __restrict__ bo,
        float* __restrict__ out) {
    __shared__ ushort As[2][128][32];   // rows = p
    __shared__ ushort Bs[2][128][32];   // rows = o
    const int m0 = blockIdx.x * 128;
    const int n0 = blockIdx.y * 128;
    const int t    = threadIdx.x;
    const int wave = t >> 6, lane = t & 63;
    const int wm = (wave >> 1) * 64, wn = (wave & 1) * 64;
    const int lrow = lane & 15, loct = lane >> 4;

    const int srow = t >> 2;
    const int skb  = (t & 3) * 8;
    const ushort* gA = po  + (m0 + srow) * INNER + skb;
    const ushort* gB = Wob + (n0 + srow) * INNER + skb;

    f32x4 acc[4][4];
#pragma unroll
    for (int i = 0; i < 4; i++)
#pragma unroll
        for (int j = 0; j < 4; j++) acc[i][j] = (f32x4){0.f, 0.f, 0.f, 0.f};

#define STAGE2(buf, c0)                                               \
    do {                                                              \
        async16(gA + (c0),              &As[buf][wave * 16][0]);      \
        async16(gA + 64 * INNER + (c0), &As[buf][64 + wave * 16][0]); \
        async16(gB + (c0),              &Bs[buf][wave * 16][0]);      \
        async16(gB + 64 * INNER + (c0), &Bs[buf][64 + wave * 16][0]); \
    } while (0)

    STAGE2(0, 0);
    __syncthreads();
    int cur = 0;
    const int NT = INNER / 32;             // 16
    for (int it = 0; it < NT; ++it) {
        if (it + 1 < NT) STAGE2(cur ^ 1, (it + 1) * 32);
        short8 a[4], bb[4];
#pragma unroll
        for (int i = 0; i < 4; i++)
            a[i] = *reinterpret_cast<const short8*>(&As[cur][wm + i * 16 + lrow][loct * 8]);
#pragma unroll
        for (int j = 0; j < 4; j++)
            bb[j] = *reinterpret_cast<const short8*>(&Bs[cur][wn + j * 16 + lrow][loct * 8]);
#pragma unroll
        for (int i = 0; i < 4; i++)
#pragma unroll
            for (int j = 0; j < 4; j++)
                acc[i][j] = __builtin_amdgcn_mfma_f32_16x16x32_bf16(a[i], bb[j], acc[i][j], 0, 0, 0);
        __syncthreads();
        cur ^= 1;
    }
#undef STAGE2

    const int bb_ = m0 >> 10;
    const int p0  = m0 & 1023;
#pragma unroll
    for (int i = 0; i < 4; i++)
#pragma unroll
        for (int j = 0; j < 4; j++) {
            int o  = n0 + wn + j * 16 + lrow;
            int pp = p0 + wm + i * 16 + loct * 4;
            float bias = bo[o];
            float4 v = make_float4(acc[i][j].x + bias, acc[i][j].y + bias,
                                   acc[i][j].z + bias, acc[i][j].w + bias);
            *reinterpret_cast<float4*>(&out[(bb_ * CIN + o) * NPIX + pp]) = v;
        }
}

// ---------------------------------------------------------------------------
extern "C" void kernel_launch(void* const* d_in, const int* in_sizes, int n_in,
                              void* d_out, int out_size, void* d_ws, size_t ws_size,
                              hipStream_t stream) {
    const float* x   = (const float*)d_in[0];
    const float* Wq  = (const float*)d_in[1];
    const float* Wkv = (const float*)d_in[2];
    const float* Wo  = (const float*)d_in[3];
    const float* bo  = (const float*)d_in[4];

    float* out  = (float*)d_out;
    float* attn = out + BATCH * CIN * NPIX;

    ushort* xT     = (ushort*)d_ws;               // 16384*256
    ushort* Wqkv_b = xT + 16384 * CIN;            // 1536*256
    ushort* Wob    = Wqkv_b + NQKV * CIN;         // 256*512
    ushort* qkv    = Wob + CIN * INNER;           // 16384*1536
    ushort* po     = qkv + 16384 * NQKV;          // 16384*512

    prep_all<<<3072, 256, 0, stream>>>(x, Wq, Wkv, Wo, xT, Wqkv_b, Wob);

    gemm_qkv<<<1536, 256, 0, stream>>>(xT, Wqkv_b, qkv);

    attn_kernel<<<16384 / 4, 256, 0, stream>>>(qkv, po, attn);

    gemm_out<<<dim3(128, 2), 256, 0, stream>>>(po, Wob, bo, out);
}